// Round 6
// baseline (334.232 us; speedup 1.0000x reference)
//
#include <hip/hip_runtime.h>
#include <hip/hip_bf16.h>

#define HEADS   16
#define S_LEN   2048
#define BATCH   2
#define MTOT    (BATCH * S_LEN)   // 4096
#define HIDDEN  2048
#define SCALE   0.125f
#define QKD_LD  2688              // fused (kv_down | q) output row stride

typedef __attribute__((ext_vector_type(8))) short          bf16x8;
typedef __attribute__((ext_vector_type(8))) unsigned short u16x8;
typedef __attribute__((ext_vector_type(4))) unsigned short u16x4;
typedef __attribute__((ext_vector_type(4))) float          f32x4;

__device__ __forceinline__ unsigned short f2bf(float f) {
    union { float f; unsigned u; } v; v.f = f;
    unsigned r = v.u + 0x7FFFu + ((v.u >> 16) & 1u);
    return (unsigned short)(r >> 16);
}

// packed f32x2 -> bf16x2 (RTNE): D.lo = bf16(a), D.hi = bf16(b)
__device__ __forceinline__ unsigned cvtpk(float a, float b) {
    unsigned r;
    asm("v_cvt_pk_bf16_f32 %0, %1, %2" : "=v"(r) : "v"(a), "v"(b));
    return r;
}

__device__ __forceinline__ void gld16(const void* g, const void* l) {
    __builtin_amdgcn_global_load_lds(
        (const __attribute__((address_space(1))) void*)g,
        (__attribute__((address_space(3))) void*)l, 16, 0, 0);
}

// ---------------------------------------------------------------------------
// elementwise f32 -> bf16 cast (8 elems/thread)
// ---------------------------------------------------------------------------
__global__ __launch_bounds__(256)
void cast_bf16(const float* __restrict__ in, unsigned short* __restrict__ out)
{
    const size_t i = ((size_t)blockIdx.x * 256 + threadIdx.x) * 8;
    float4 a = *(const float4*)&in[i];
    float4 b = *(const float4*)&in[i + 4];
    u16x8 o;
    o[0] = f2bf(a.x); o[1] = f2bf(a.y); o[2] = f2bf(a.z); o[3] = f2bf(a.w);
    o[4] = f2bf(b.x); o[5] = f2bf(b.y); o[6] = f2bf(b.z); o[7] = f2bf(b.w);
    *(u16x8*)&out[i] = o;
}

// ---------------------------------------------------------------------------
// transpose + cast weights: W f32 [K][N] -> Wt bf16 [Npad][K]
// ---------------------------------------------------------------------------
__global__ __launch_bounds__(256)
void tc_w(const float* __restrict__ W, int N, int K, unsigned short* __restrict__ Wt)
{
    __shared__ float Tf[64][68];
    const int t  = threadIdx.x;
    const int n0 = blockIdx.x * 64, k0 = blockIdx.y * 64;
    if (n0 >= N) {
        u16x8 z = {0,0,0,0,0,0,0,0};
#pragma unroll
        for (int ii = 0; ii < 2; ii++) {
            int idx = t + 256 * ii;
            int rn = idx >> 3, c8 = (idx & 7) * 8;
            *(u16x8*)&Wt[(size_t)(n0 + rn) * K + k0 + c8] = z;
        }
        return;
    }
#pragma unroll
    for (int ii = 0; ii < 4; ii++) {
        int idx = t + 256 * ii;
        int rk = idx >> 4, c4 = (idx & 15) * 4;
        *(float4*)&Tf[rk][c4] = *(const float4*)&W[(size_t)(k0 + rk) * N + n0 + c4];
    }
    __syncthreads();
#pragma unroll
    for (int ii = 0; ii < 2; ii++) {
        int idx = t + 256 * ii;
        int rn = idx >> 3, c8 = (idx & 7) * 8;
        u16x8 o;
#pragma unroll
        for (int j = 0; j < 8; j++) o[j] = f2bf(Tf[c8 + j][rn]);
        *(u16x8*)&Wt[(size_t)(n0 + rn) * K + k0 + c8] = o;
    }
}

// ---------------------------------------------------------------------------
// V transpose: kvu bf16 [MTOT][3072] (v = cols h*192+64..191) -> vT [B*H*128][S]
// ---------------------------------------------------------------------------
__global__ __launch_bounds__(256)
void transpose_v(const unsigned short* __restrict__ kvu, unsigned short* __restrict__ vT)
{
    __shared__ unsigned short Ts[64][80];
    const int t  = threadIdx.x;
    const int s0 = blockIdx.x * 64;
    const int h  = blockIdx.y >> 1, d0 = (blockIdx.y & 1) * 64;
    const int b  = blockIdx.z;
    const size_t base = (size_t)b * S_LEN;
#pragma unroll
    for (int ii = 0; ii < 2; ii++) {
        int idx = t + 256 * ii;
        int rs = idx >> 3, c8 = (idx & 7) * 8;
        *(u16x8*)&Ts[rs][c8] =
            *(const u16x8*)&kvu[(base + s0 + rs) * 3072 + h * 192 + 64 + d0 + c8];
    }
    __syncthreads();
    const size_t bh = (size_t)(b * HEADS + h);
#pragma unroll
    for (int ii = 0; ii < 2; ii++) {
        int idx = t + 256 * ii;
        int rd = idx >> 3, c8 = (idx & 7) * 8;
        u16x8 o;
#pragma unroll
        for (int j = 0; j < 8; j++) o[j] = Ts[c8 + j][rd];
        *(u16x8*)&vT[(bh * 128 + d0 + rd) * S_LEN + s0 + c8] = o;
    }
}

// ---------------------------------------------------------------------------
// bf16 MFMA GEMM (m97 structure): C[M x N] = A[M x K] @ Bt[N x K]^T
// ---------------------------------------------------------------------------
template<bool OUT_BF16>
__global__ __launch_bounds__(256)
void gemm_bf16(const unsigned short* __restrict__ A, int lda, int K,
               const unsigned short* __restrict__ Bt,
               void* __restrict__ C, int N, int ldc)
{
    __shared__ unsigned short As[128 * 32];
    __shared__ unsigned short Bs[128 * 32];
    const int t = threadIdx.x, lane = t & 63, w = t >> 6;
    const int l15 = lane & 15, lg = lane >> 4;
    const int row0 = blockIdx.y * 128, col0 = blockIdx.x * 128;
    const int wr = w >> 1, wc = w & 1;

    f32x4 acc[4][4] = {};

    for (int k0 = 0; k0 < K; k0 += 32) {
        __syncthreads();
#pragma unroll
        for (int ii = 0; ii < 2; ii++) {
            int u = (ii * 4 + w) * 64 + lane;
            gld16(&A[(size_t)(row0 + (u >> 2)) * lda + k0 + (u & 3) * 8],
                  (char*)As + (ii * 4 + w) * 1024);
            gld16(&Bt[(size_t)(col0 + (u >> 2)) * K + k0 + (u & 3) * 8],
                  (char*)Bs + (ii * 4 + w) * 1024);
        }
        __syncthreads();
        bf16x8 af[4], bb[4];
#pragma unroll
        for (int m = 0; m < 4; m++)
            af[m] = *(const bf16x8*)&As[(wr * 64 + m * 16 + l15) * 32 + lg * 8];
#pragma unroll
        for (int n = 0; n < 4; n++)
            bb[n] = *(const bf16x8*)&Bs[(wc * 64 + n * 16 + l15) * 32 + lg * 8];
#pragma unroll
        for (int m = 0; m < 4; m++)
#pragma unroll
            for (int n = 0; n < 4; n++)
                acc[m][n] = __builtin_amdgcn_mfma_f32_16x16x32_bf16(
                    af[m], bb[n], acc[m][n], 0, 0, 0);
    }

#pragma unroll
    for (int m = 0; m < 4; m++)
#pragma unroll
        for (int n = 0; n < 4; n++) {
            int col = col0 + wc * 64 + n * 16 + l15;
            if (col < N) {
#pragma unroll
                for (int r = 0; r < 4; r++) {
                    int row = row0 + wr * 64 + m * 16 + lg * 4 + r;
                    if (OUT_BF16)
                        ((unsigned short*)C)[(size_t)row * ldc + col] = f2bf(acc[m][n][r]);
                    else
                        ((float*)C)[(size_t)row * ldc + col] = acc[m][n][r];
                }
            }
        }
}

// ---------------------------------------------------------------------------
// MFMA flash attention, swapped-QK^T, occupancy-optimized.
// Block = 4 waves x 16 q-rows = 64 q-rows per (b,h); grid 1024 -> 4 blocks/CU
// (LDS = 40KB: single-buffered K/V + per-wave P). Latency hidden by TLP
// across blocks. Defer-max (THR=8) skips rescale/broadcast on stable tiles.
// ---------------------------------------------------------------------------
__global__ __launch_bounds__(256, 4)
void mla_attn_mfma(const unsigned short* __restrict__ qkd,   // [MTOT][2688]: rope at 512, q at 640
                   const unsigned short* __restrict__ kvu,   // [MTOT][3072]
                   const unsigned short* __restrict__ vT,    // [B*H*128][S]
                   const float* __restrict__ mask,           // [S][S]
                   unsigned short* __restrict__ ctxb)        // [MTOT][2048]
{
    __shared__ unsigned short Ks[64 * 128];   // [key][d], chunks XOR-swizzled
    __shared__ unsigned short Vs[128 * 64];   // [d][key], chunks XOR-swizzled
    __shared__ unsigned short Pl[4][16 * 64]; // per-wave P, XOR-swizzled
    const int t = threadIdx.x, lane = t & 63, w = t >> 6;
    const int l15 = lane & 15, lg = lane >> 4;
    const int h = blockIdx.y, b = blockIdx.z;
    const int q0 = blockIdx.x * 64 + w * 16;   // this wave's 16 q-rows
    const size_t base = (size_t)b * S_LEN;
    const size_t bh = (size_t)(b * HEADS + h);
    const unsigned short* qb = qkd + 640;
    unsigned short* Pw = &Pl[w][0];
    const unsigned psw = (unsigned)(l15 & 7) << 4;  // P swizzle

    // Q fragments (B-operand): lane holds q-col l15, k-dims lg*8 per kk
    bf16x8 qf[4];
#pragma unroll
    for (int kk = 0; kk < 4; kk++)
        qf[kk] = *(const bf16x8*)&qb[(base + q0 + l15) * QKD_LD
                                     + h * 128 + kk * 32 + lg * 8];

    f32x4 octx[8] = {};
    float mrun = -INFINITY, lrun = 0.f;

    const float* mrow = &mask[(size_t)(q0 + l15) * S_LEN + lg * 4];

    const int NT = S_LEN / 64;
    for (int kt = 0; kt < NT; kt++) {
        const int s0 = kt * 64;

        // barrier 1: all waves done computing tile kt-1 -> buffers free
        __builtin_amdgcn_s_barrier();

        // ---- stage K (rope|nope) and V, pre-swizzled global source ----
#pragma unroll
        for (int ii = 0; ii < 4; ii++) {
            int u = (ii * 4 + w) * 64 + lane;
            { // K: row=key (0..63), 16 chunks of 8 bf16
                int row = u >> 4, x = u & 15, y = x ^ (row & 7);
                const unsigned short* g = (y < 8)
                    ? &qkd[(base + s0 + row) * QKD_LD + 512 + y * 8]
                    : &kvu[(base + s0 + row) * 3072 + h * 192 + (y - 8) * 8];
                gld16(g, (char*)Ks + (ii * 4 + w) * 1024);
            }
            { // V: row=d (0..127), 8 chunks of 8 bf16
                int d = u >> 3, x = u & 7, y = x ^ (d & 7);
                gld16(&vT[(bh * 128 + d) * S_LEN + s0 + y * 8],
                      (char*)Vs + (ii * 4 + w) * 1024);
            }
        }
        __builtin_amdgcn_sched_barrier(0);

        // mask loads issued after stage: vmcnt(4) drains stage, keeps these
        float4 mv[4];
#pragma unroll
        for (int n = 0; n < 4; n++) mv[n] = *(const float4*)&mrow[s0 + n * 16];
        __builtin_amdgcn_sched_barrier(0);
        asm volatile("s_waitcnt vmcnt(4)" ::: "memory");
        // barrier 2: stage complete block-wide -> K/V valid
        __builtin_amdgcn_s_barrier();

        // ---- scores S[key][q]: sc[n][r] = S[n*16+lg*4+r][q0+l15] ----
        f32x4 sc[4] = {};
        __builtin_amdgcn_s_setprio(1);
#pragma unroll
        for (int n = 0; n < 4; n++) {
            const int key = n * 16 + l15;
#pragma unroll
            for (int kk = 0; kk < 4; kk++) {
                const int x = (kk * 4 + lg) ^ (key & 7);
                bf16x8 kf = *(const bf16x8*)&Ks[key * 128 + x * 8];
                sc[n] = __builtin_amdgcn_mfma_f32_16x16x32_bf16(kf, qf[kk], sc[n], 0, 0, 0);
            }
        }
        __builtin_amdgcn_s_setprio(0);

        // ---- online softmax (row = l15, spread over lg via shfl 16/32) ----
        float sv[4][4];
#pragma unroll
        for (int n = 0; n < 4; n++) {
            sv[n][0] = sc[n][0] * SCALE + mv[n].x;
            sv[n][1] = sc[n][1] * SCALE + mv[n].y;
            sv[n][2] = sc[n][2] * SCALE + mv[n].z;
            sv[n][3] = sc[n][3] * SCALE + mv[n].w;
        }
        float loc = sv[0][0];
#pragma unroll
        for (int n = 0; n < 4; n++)
#pragma unroll
            for (int r = 0; r < 4; r++) loc = fmaxf(loc, sv[n][r]);
        loc = fmaxf(loc, __shfl_xor(loc, 16));
        loc = fmaxf(loc, __shfl_xor(loc, 32));

        // defer-max: only rescale when the running max grew by > 8
        if (!__all((int)(loc <= mrun + 8.f))) {
            float mnew = fmaxf(mrun, loc);
            float esc = __expf(mrun - mnew);
            mrun = mnew;
            lrun *= esc;
            float e_bc[4];
#pragma unroll
            for (int r = 0; r < 4; r++) e_bc[r] = __shfl(esc, lg * 4 + r);
#pragma unroll
            for (int vn = 0; vn < 8; vn++)
#pragma unroll
                for (int r = 0; r < 4; r++) octx[vn][r] *= e_bc[r];
        }

        float ls = 0.f;
#pragma unroll
        for (int n = 0; n < 4; n++) {
            float p0 = __expf(sv[n][0] - mrun), p1 = __expf(sv[n][1] - mrun);
            float p2 = __expf(sv[n][2] - mrun), p3 = __expf(sv[n][3] - mrun);
            ls += (p0 + p1) + (p2 + p3);
            union { unsigned u[2]; u16x4 v; } pk;
            pk.u[0] = cvtpk(p0, p1);
            pk.u[1] = cvtpk(p2, p3);
            *(u16x4*)((char*)Pw + l15 * 128 + ((n * 32 + lg * 8) ^ psw)) = pk.v;
        }
        ls += __shfl_xor(ls, 16);
        ls += __shfl_xor(ls, 32);
        lrun += ls;

        // compiler memory fence: P stores must not be reordered past PV loads
        asm volatile("" ::: "memory");

        // ---- PV ----
        bf16x8 paf[2];
#pragma unroll
        for (int kk = 0; kk < 2; kk++)
            paf[kk] = *(const bf16x8*)((char*)Pw + l15 * 128 + ((kk * 64 + lg * 16) ^ psw));
        __builtin_amdgcn_s_setprio(1);
#pragma unroll
        for (int vn = 0; vn < 8; vn++) {
            const int d = vn * 16 + l15;
#pragma unroll
            for (int kk = 0; kk < 2; kk++) {
                const int x = (kk * 4 + lg) ^ (d & 7);
                bf16x8 vf = *(const bf16x8*)&Vs[d * 64 + x * 8];
                octx[vn] = __builtin_amdgcn_mfma_f32_16x16x32_bf16(paf[kk], vf, octx[vn], 0, 0, 0);
            }
        }
        __builtin_amdgcn_s_setprio(0);
    }

    // ---- normalize + write ----
    float inv[4];
#pragma unroll
    for (int r = 0; r < 4; r++) inv[r] = 1.0f / __shfl(lrun, lg * 4 + r);
#pragma unroll
    for (int vn = 0; vn < 8; vn++)
#pragma unroll
        for (int r = 0; r < 4; r++)
            ctxb[(base + q0 + lg * 4 + r) * 2048 + h * 128 + vn * 16 + l15]
                = f2bf(octx[vn][r] * inv[r]);
}

// ---------------------------------------------------------------------------
extern "C" void kernel_launch(void* const* d_in, const int* in_sizes, int n_in,
                              void* d_out, int out_size, void* d_ws, size_t ws_size,
                              hipStream_t stream)
{
    const float* hidden = (const float*)d_in[0];
    const float* mask   = (const float*)d_in[1];
    const float* W_down = (const float*)d_in[2];
    const float* W_up   = (const float*)d_in[3];
    const float* W_q    = (const float*)d_in[4];
    const float* W_o    = (const float*)d_in[5];
    float* out = (float*)d_out;

    unsigned short* p = (unsigned short*)d_ws;
    unsigned short* hb      = p; p += (size_t)MTOT * 2048;     // bf16 hidden
    unsigned short* qkd     = p; p += (size_t)MTOT * QKD_LD;   // kv_down(640) | q(2048)
    unsigned short* kvu_b   = p; p += (size_t)MTOT * 3072;
    unsigned short* vTb     = p; p += (size_t)BATCH * HEADS * 128 * S_LEN;
    unsigned short* ctxb    = p; p += (size_t)MTOT * 2048;
    unsigned short* Wt_cat  = p; p += (size_t)QKD_LD * 2048;   // W_down^T (640) | W_q^T (2048)
    unsigned short* Wt_up   = p; p += (size_t)3072 * 512;
    unsigned short* Wt_o    = p; p += (size_t)2048 * 2048;

    dim3 blk(256);
    cast_bf16<<<dim3(MTOT * 2048 / (256 * 8)), blk, 0, stream>>>(hidden, hb);
    tc_w<<<dim3(10, 32), blk, 0, stream>>>(W_down, 576, 2048, Wt_cat);
    tc_w<<<dim3(32, 32), blk, 0, stream>>>(W_q, 2048, 2048, Wt_cat + (size_t)640 * 2048);
    tc_w<<<dim3(48, 8),  blk, 0, stream>>>(W_up, 3072, 512, Wt_up);
    tc_w<<<dim3(32, 32), blk, 0, stream>>>(W_o, 2048, 2048, Wt_o);

    // fused (kv_down | q) = hb @ Wt_cat^T
    gemm_bf16<true><<<dim3(QKD_LD / 128, 32), blk, 0, stream>>>(
        hb, 2048, 2048, Wt_cat, qkd, QKD_LD, QKD_LD);
    // kv = kv_compressed @ W_up  (A = qkd cols 0..511, lda=2688)
    gemm_bf16<true><<<dim3(24, 32), blk, 0, stream>>>(
        qkd, QKD_LD, 512, Wt_up, kvu_b, 3072, 3072);

    transpose_v<<<dim3(S_LEN / 64, 2 * HEADS, BATCH), blk, 0, stream>>>(kvu_b, vTb);

    mla_attn_mfma<<<dim3(S_LEN / 64, HEADS, BATCH), blk, 0, stream>>>(
        qkd, kvu_b, vTb, mask, ctxb);

    gemm_bf16<false><<<dim3(16, 32), blk, 0, stream>>>(
        ctxb, 2048, 2048, Wt_o, out, 2048, 2048);
}

// Round 7
// 297.807 us; speedup vs baseline: 1.1223x; 1.1223x over previous
//
#include <hip/hip_runtime.h>
#include <hip/hip_bf16.h>

#define HEADS   16
#define S_LEN   2048
#define BATCH   2
#define MTOT    (BATCH * S_LEN)   // 4096
#define HIDDEN  2048
#define SCALE   0.125f
#define QKD_LD  2688              // fused (kv_down | q) output row stride

typedef __attribute__((ext_vector_type(8))) short          bf16x8;
typedef __attribute__((ext_vector_type(8))) unsigned short u16x8;
typedef __attribute__((ext_vector_type(4))) unsigned short u16x4;
typedef __attribute__((ext_vector_type(4))) float          f32x4;

__device__ __forceinline__ unsigned short f2bf(float f) {
    union { float f; unsigned u; } v; v.f = f;
    unsigned r = v.u + 0x7FFFu + ((v.u >> 16) & 1u);
    return (unsigned short)(r >> 16);
}

// packed f32x2 -> bf16x2 (RTNE): D.lo = bf16(a), D.hi = bf16(b)
__device__ __forceinline__ unsigned cvtpk(float a, float b) {
    unsigned r;
    asm("v_cvt_pk_bf16_f32 %0, %1, %2" : "=v"(r) : "v"(a), "v"(b));
    return r;
}

__device__ __forceinline__ void gld16(const void* g, const void* l) {
    __builtin_amdgcn_global_load_lds(
        (const __attribute__((address_space(1))) void*)g,
        (__attribute__((address_space(3))) void*)l, 16, 0, 0);
}

// ---------------------------------------------------------------------------
// elementwise f32 -> bf16 cast (8 elems/thread)
// ---------------------------------------------------------------------------
__global__ __launch_bounds__(256)
void cast_bf16(const float* __restrict__ in, unsigned short* __restrict__ out)
{
    const size_t i = ((size_t)blockIdx.x * 256 + threadIdx.x) * 8;
    float4 a = *(const float4*)&in[i];
    float4 b = *(const float4*)&in[i + 4];
    u16x8 o;
    o[0] = f2bf(a.x); o[1] = f2bf(a.y); o[2] = f2bf(a.z); o[3] = f2bf(a.w);
    o[4] = f2bf(b.x); o[5] = f2bf(b.y); o[6] = f2bf(b.z); o[7] = f2bf(b.w);
    *(u16x8*)&out[i] = o;
}

// ---------------------------------------------------------------------------
// transpose + cast weights: W f32 [K][N] -> Wt bf16 [Npad][K]
// ---------------------------------------------------------------------------
__global__ __launch_bounds__(256)
void tc_w(const float* __restrict__ W, int N, int K, unsigned short* __restrict__ Wt)
{
    __shared__ float Tf[64][68];
    const int t  = threadIdx.x;
    const int n0 = blockIdx.x * 64, k0 = blockIdx.y * 64;
    if (n0 >= N) {
        u16x8 z = {0,0,0,0,0,0,0,0};
#pragma unroll
        for (int ii = 0; ii < 2; ii++) {
            int idx = t + 256 * ii;
            int rn = idx >> 3, c8 = (idx & 7) * 8;
            *(u16x8*)&Wt[(size_t)(n0 + rn) * K + k0 + c8] = z;
        }
        return;
    }
#pragma unroll
    for (int ii = 0; ii < 4; ii++) {
        int idx = t + 256 * ii;
        int rk = idx >> 4, c4 = (idx & 15) * 4;
        *(float4*)&Tf[rk][c4] = *(const float4*)&W[(size_t)(k0 + rk) * N + n0 + c4];
    }
    __syncthreads();
#pragma unroll
    for (int ii = 0; ii < 2; ii++) {
        int idx = t + 256 * ii;
        int rn = idx >> 3, c8 = (idx & 7) * 8;
        u16x8 o;
#pragma unroll
        for (int j = 0; j < 8; j++) o[j] = f2bf(Tf[c8 + j][rn]);
        *(u16x8*)&Wt[(size_t)(n0 + rn) * K + k0 + c8] = o;
    }
}

// ---------------------------------------------------------------------------
// V transpose: kvu bf16 [MTOT][3072] (v = cols h*192+64..191) -> vT [B*H*128][S]
// ---------------------------------------------------------------------------
__global__ __launch_bounds__(256)
void transpose_v(const unsigned short* __restrict__ kvu, unsigned short* __restrict__ vT)
{
    __shared__ unsigned short Ts[64][80];
    const int t  = threadIdx.x;
    const int s0 = blockIdx.x * 64;
    const int h  = blockIdx.y >> 1, d0 = (blockIdx.y & 1) * 64;
    const int b  = blockIdx.z;
    const size_t base = (size_t)b * S_LEN;
#pragma unroll
    for (int ii = 0; ii < 2; ii++) {
        int idx = t + 256 * ii;
        int rs = idx >> 3, c8 = (idx & 7) * 8;
        *(u16x8*)&Ts[rs][c8] =
            *(const u16x8*)&kvu[(base + s0 + rs) * 3072 + h * 192 + 64 + d0 + c8];
    }
    __syncthreads();
    const size_t bh = (size_t)(b * HEADS + h);
#pragma unroll
    for (int ii = 0; ii < 2; ii++) {
        int idx = t + 256 * ii;
        int rd = idx >> 3, c8 = (idx & 7) * 8;
        u16x8 o;
#pragma unroll
        for (int j = 0; j < 8; j++) o[j] = Ts[c8 + j][rd];
        *(u16x8*)&vT[(bh * 128 + d0 + rd) * S_LEN + s0 + c8] = o;
    }
}

// ---------------------------------------------------------------------------
// bf16 MFMA GEMM (m97 structure): C[M x N] = A[M x K] @ Bt[N x K]^T
// ---------------------------------------------------------------------------
template<bool OUT_BF16>
__global__ __launch_bounds__(256)
void gemm_bf16(const unsigned short* __restrict__ A, int lda, int K,
               const unsigned short* __restrict__ Bt,
               void* __restrict__ C, int N, int ldc)
{
    __shared__ unsigned short As[128 * 32];
    __shared__ unsigned short Bs[128 * 32];
    const int t = threadIdx.x, lane = t & 63, w = t >> 6;
    const int l15 = lane & 15, lg = lane >> 4;
    const int row0 = blockIdx.y * 128, col0 = blockIdx.x * 128;
    const int wr = w >> 1, wc = w & 1;

    f32x4 acc[4][4] = {};

    for (int k0 = 0; k0 < K; k0 += 32) {
        __syncthreads();
#pragma unroll
        for (int ii = 0; ii < 2; ii++) {
            int u = (ii * 4 + w) * 64 + lane;
            gld16(&A[(size_t)(row0 + (u >> 2)) * lda + k0 + (u & 3) * 8],
                  (char*)As + (ii * 4 + w) * 1024);
            gld16(&Bt[(size_t)(col0 + (u >> 2)) * K + k0 + (u & 3) * 8],
                  (char*)Bs + (ii * 4 + w) * 1024);
        }
        __syncthreads();
        bf16x8 af[4], bb[4];
#pragma unroll
        for (int m = 0; m < 4; m++)
            af[m] = *(const bf16x8*)&As[(wr * 64 + m * 16 + l15) * 32 + lg * 8];
#pragma unroll
        for (int n = 0; n < 4; n++)
            bb[n] = *(const bf16x8*)&Bs[(wc * 64 + n * 16 + l15) * 32 + lg * 8];
#pragma unroll
        for (int m = 0; m < 4; m++)
#pragma unroll
            for (int n = 0; n < 4; n++)
                acc[m][n] = __builtin_amdgcn_mfma_f32_16x16x32_bf16(
                    af[m], bb[n], acc[m][n], 0, 0, 0);
    }

#pragma unroll
    for (int m = 0; m < 4; m++)
#pragma unroll
        for (int n = 0; n < 4; n++) {
            int col = col0 + wc * 64 + n * 16 + l15;
            if (col < N) {
#pragma unroll
                for (int r = 0; r < 4; r++) {
                    int row = row0 + wr * 64 + m * 16 + lg * 4 + r;
                    if (OUT_BF16)
                        ((unsigned short*)C)[(size_t)row * ldc + col] = f2bf(acc[m][n][r]);
                    else
                        ((float*)C)[(size_t)row * ldc + col] = acc[m][n][r];
                }
            }
        }
}

// ---------------------------------------------------------------------------
// MFMA flash attention, swapped-QK^T, 2-phase prefetch with correct vmcnt
// ordering + register-double-buffered mask + defer-max.
// Block = 4 waves x 32 q-rows = 128 q-rows per (b,h). K-tiles of 64 keys,
// K+V double-buffered. Per tile: barrier -> issue mask(kt+1) loads ->
// issue stage(kt+1) -> vmcnt(24) (24 = exactly the younger mask+stage ops,
// so only old stage(kt) remnants drain -> zero exposed latency) -> barrier
// -> QK/softmax (mask from regs)/PV -> copy mask regs (vmcnt(16), free).
// ---------------------------------------------------------------------------
__global__ __launch_bounds__(256, 2)
void mla_attn_mfma(const unsigned short* __restrict__ qkd,   // [MTOT][2688]: rope at 512, q at 640
                   const unsigned short* __restrict__ kvu,   // [MTOT][3072]
                   const unsigned short* __restrict__ vT,    // [B*H*128][S]
                   const float* __restrict__ mask,           // [S][S]
                   unsigned short* __restrict__ ctxb)        // [MTOT][2048]
{
    __shared__ unsigned short KV[2][64 * 128 + 128 * 64];  // [buf]{K,V}, 32KB each
    __shared__ unsigned short Pl[4][32 * 64];              // per-wave P, swizzled
    const int t = threadIdx.x, lane = t & 63, w = t >> 6;
    const int l15 = lane & 15, lg = lane >> 4;
    const int h = blockIdx.y, b = blockIdx.z;
    const int q0 = blockIdx.x * 128 + w * 32;   // this wave's 32 q-rows
    const size_t base = (size_t)b * S_LEN;
    const size_t bh = (size_t)(b * HEADS + h);
    const unsigned short* qb = qkd + 640;
    unsigned short* Pw = &Pl[w][0];
    const unsigned psw = (unsigned)(l15 & 7) << 4;  // P swizzle

    // Q fragments (B-operand): lane holds q-col (m*16+l15), k-dims lg*8 per kk
    bf16x8 qf[2][4];
#pragma unroll
    for (int m = 0; m < 2; m++)
#pragma unroll
        for (int kk = 0; kk < 4; kk++)
            qf[m][kk] = *(const bf16x8*)&qb[(base + q0 + m * 16 + l15) * QKD_LD
                                            + h * 128 + kk * 32 + lg * 8];

    f32x4 octx[2][8] = {};
    float mrun[2] = {-INFINITY, -INFINITY};
    float lrun[2] = {0.f, 0.f};

    const float* mrow0 = &mask[(size_t)(q0 + l15) * S_LEN + lg * 4];
    const float* mrow1 = mrow0 + (size_t)16 * S_LEN;

    // ---- stage helper: 16 gld16 into KV[buf] ----
    auto STAGE = [&](int buf, int s0) {
        unsigned short* Kb = &KV[buf][0];
        unsigned short* Vb = &KV[buf][64 * 128];
#pragma unroll
        for (int ii = 0; ii < 4; ii++) {
            int u = (ii * 4 + w) * 64 + lane;
            { // K: row=key (0..63), 16 chunks of 8 bf16, rope|nope
                int row = u >> 4, x = u & 15, y = x ^ (row & 7);
                const unsigned short* g = (y < 8)
                    ? &qkd[(base + s0 + row) * QKD_LD + 512 + y * 8]
                    : &kvu[(base + s0 + row) * 3072 + h * 192 + (y - 8) * 8];
                gld16(g, (char*)Kb + (ii * 4 + w) * 1024);
            }
            { // V: row=d (0..127), 8 chunks of 8 bf16
                int d = u >> 3, x = u & 7, y = x ^ (d & 7);
                gld16(&vT[(bh * 128 + d) * S_LEN + s0 + y * 8],
                      (char*)Vb + (ii * 4 + w) * 1024);
            }
        }
    };

    const int NT = S_LEN / 64;
    // prologue: stage tile 0, then mask tile 0 (stage older than mask)
    STAGE(0, 0);
    float4 mvc[2][4], mvn[2][4];
#pragma unroll
    for (int n = 0; n < 4; n++) {
        mvc[0][n] = *(const float4*)&mrow0[n * 16];
        mvc[1][n] = *(const float4*)&mrow1[n * 16];
    }

    for (int kt = 0; kt < NT; kt++) {
        const int cur = kt & 1;
        const int s0 = kt * 64;
        const unsigned short* Ks = &KV[cur][0];
        const unsigned short* Vs = &KV[cur][64 * 128];

        // barrier 1: all waves done with PV(kt-1) -> buf[cur^1] is free
        __builtin_amdgcn_s_barrier();

        if (kt + 1 < NT) {
            // mask(kt+1) first (older than the stage below -> copy at loop
            // end only needs vmcnt(16), leaving the K/V prefetch in flight)
#pragma unroll
            for (int n = 0; n < 4; n++) {
                mvn[0][n] = *(const float4*)&mrow0[s0 + 64 + n * 16];
                mvn[1][n] = *(const float4*)&mrow1[s0 + 64 + n * 16];
            }
            __builtin_amdgcn_sched_barrier(0);
            STAGE(cur ^ 1, s0 + 64);
            __builtin_amdgcn_sched_barrier(0);
            // 24 younger ops (8 mask + 16 stage) -> drains only stage(kt) remnants
            asm volatile("s_waitcnt vmcnt(24)" ::: "memory");
        } else {
            __builtin_amdgcn_sched_barrier(0);
            asm volatile("s_waitcnt vmcnt(0)" ::: "memory");
        }
        __builtin_amdgcn_sched_barrier(0);
        // barrier 2: all waves' stage(kt) complete -> buf[cur] valid
        __builtin_amdgcn_s_barrier();

        // ---- scores S[key][q]: sc[m][n][r] = S[n*16+lg*4+r][m*16+l15] ----
        f32x4 sc[2][4] = {};
        __builtin_amdgcn_s_setprio(1);
#pragma unroll
        for (int n = 0; n < 4; n++) {
            const int key = n * 16 + l15;
#pragma unroll
            for (int kk = 0; kk < 4; kk++) {
                const int x = (kk * 4 + lg) ^ (key & 7);
                bf16x8 kf = *(const bf16x8*)&Ks[key * 128 + x * 8];
                sc[0][n] = __builtin_amdgcn_mfma_f32_16x16x32_bf16(kf, qf[0][kk], sc[0][n], 0, 0, 0);
                sc[1][n] = __builtin_amdgcn_mfma_f32_16x16x32_bf16(kf, qf[1][kk], sc[1][n], 0, 0, 0);
            }
        }
        __builtin_amdgcn_s_setprio(0);

        // ---- online softmax per q-row (lane-local row = l15, per m) ----
        float sv[2][4][4];
        float loc[2];
#pragma unroll
        for (int m = 0; m < 2; m++) {
#pragma unroll
            for (int n = 0; n < 4; n++) {
                sv[m][n][0] = sc[m][n][0] * SCALE + mvc[m][n].x;
                sv[m][n][1] = sc[m][n][1] * SCALE + mvc[m][n].y;
                sv[m][n][2] = sc[m][n][2] * SCALE + mvc[m][n].z;
                sv[m][n][3] = sc[m][n][3] * SCALE + mvc[m][n].w;
            }
            float lc = sv[m][0][0];
#pragma unroll
            for (int n = 0; n < 4; n++)
#pragma unroll
                for (int r = 0; r < 4; r++) lc = fmaxf(lc, sv[m][n][r]);
            lc = fmaxf(lc, __shfl_xor(lc, 16));
            lc = fmaxf(lc, __shfl_xor(lc, 32));
            loc[m] = lc;
        }

        // defer-max: rescale only when the running max grew by > 8
        if (!__all((int)((loc[0] <= mrun[0] + 8.f) & (loc[1] <= mrun[1] + 8.f)))) {
#pragma unroll
            for (int m = 0; m < 2; m++) {
                float mnew = fmaxf(mrun[m], loc[m]);
                float esc = __expf(mrun[m] - mnew);
                mrun[m] = mnew;
                lrun[m] *= esc;
                float e_bc[4];
#pragma unroll
                for (int r = 0; r < 4; r++) e_bc[r] = __shfl(esc, lg * 4 + r);
#pragma unroll
                for (int vn = 0; vn < 8; vn++)
#pragma unroll
                    for (int r = 0; r < 4; r++) octx[m][vn][r] *= e_bc[r];
            }
        }

#pragma unroll
        for (int m = 0; m < 2; m++) {
            float ls = 0.f;
            const int prow = m * 16 + l15;
#pragma unroll
            for (int n = 0; n < 4; n++) {
                float p0 = __expf(sv[m][n][0] - mrun[m]), p1 = __expf(sv[m][n][1] - mrun[m]);
                float p2 = __expf(sv[m][n][2] - mrun[m]), p3 = __expf(sv[m][n][3] - mrun[m]);
                ls += (p0 + p1) + (p2 + p3);
                union { unsigned u[2]; u16x4 v; } pk;
                pk.u[0] = cvtpk(p0, p1);
                pk.u[1] = cvtpk(p2, p3);
                *(u16x4*)((char*)Pw + prow * 128 + ((n * 32 + lg * 8) ^ psw)) = pk.v;
            }
            ls += __shfl_xor(ls, 16);
            ls += __shfl_xor(ls, 32);
            lrun[m] += ls;
        }

        // compiler memory fence: P stores must not be reordered past PV loads
        asm volatile("" ::: "memory");

        // ---- PV ----
        bf16x8 paf[2][2];
#pragma unroll
        for (int m = 0; m < 2; m++) {
            const int prow = m * 16 + l15;
#pragma unroll
            for (int kk = 0; kk < 2; kk++)
                paf[m][kk] = *(const bf16x8*)((char*)Pw + prow * 128
                                              + ((kk * 64 + lg * 16) ^ psw));
        }
        __builtin_amdgcn_s_setprio(1);
#pragma unroll
        for (int vn = 0; vn < 8; vn++) {
            const int d = vn * 16 + l15;
#pragma unroll
            for (int kk = 0; kk < 2; kk++) {
                const int x = (kk * 4 + lg) ^ (d & 7);
                bf16x8 vf = *(const bf16x8*)&Vs[d * 64 + x * 8];
                octx[0][vn] = __builtin_amdgcn_mfma_f32_16x16x32_bf16(paf[0][kk], vf, octx[0][vn], 0, 0, 0);
                octx[1][vn] = __builtin_amdgcn_mfma_f32_16x16x32_bf16(paf[1][kk], vf, octx[1][vn], 0, 0, 0);
            }
        }
        __builtin_amdgcn_s_setprio(0);

        // rotate mask regs (vmcnt(16): only the 8 mask loads must retire;
        // the 16 stage(kt+1) gld_lds stay in flight)
        if (kt + 1 < NT) {
#pragma unroll
            for (int m = 0; m < 2; m++)
#pragma unroll
                for (int n = 0; n < 4; n++) mvc[m][n] = mvn[m][n];
        }
    }

    // ---- normalize + write ----
#pragma unroll
    for (int m = 0; m < 2; m++) {
        float inv[4];
#pragma unroll
        for (int r = 0; r < 4; r++) inv[r] = 1.0f / __shfl(lrun[m], lg * 4 + r);
#pragma unroll
        for (int vn = 0; vn < 8; vn++)
#pragma unroll
            for (int r = 0; r < 4; r++)
                ctxb[(base + q0 + m * 16 + lg * 4 + r) * 2048 + h * 128 + vn * 16 + l15]
                    = f2bf(octx[m][vn][r] * inv[r]);
    }
}

// ---------------------------------------------------------------------------
extern "C" void kernel_launch(void* const* d_in, const int* in_sizes, int n_in,
                              void* d_out, int out_size, void* d_ws, size_t ws_size,
                              hipStream_t stream)
{
    const float* hidden = (const float*)d_in[0];
    const float* mask   = (const float*)d_in[1];
    const float* W_down = (const float*)d_in[2];
    const float* W_up   = (const float*)d_in[3];
    const float* W_q    = (const float*)d_in[4];
    const float* W_o    = (const float*)d_in[5];
    float* out = (float*)d_out;

    unsigned short* p = (unsigned short*)d_ws;
    unsigned short* hb      = p; p += (size_t)MTOT * 2048;     // bf16 hidden
    unsigned short* qkd     = p; p += (size_t)MTOT * QKD_LD;   // kv_down(640) | q(2048)
    unsigned short* kvu_b   = p; p += (size_t)MTOT * 3072;
    unsigned short* vTb     = p; p += (size_t)BATCH * HEADS * 128 * S_LEN;
    unsigned short* ctxb    = p; p += (size_t)MTOT * 2048;
    unsigned short* Wt_cat  = p; p += (size_t)QKD_LD * 2048;   // W_down^T (640) | W_q^T (2048)
    unsigned short* Wt_up   = p; p += (size_t)3072 * 512;
    unsigned short* Wt_o    = p; p += (size_t)2048 * 2048;

    dim3 blk(256);
    cast_bf16<<<dim3(MTOT * 2048 / (256 * 8)), blk, 0, stream>>>(hidden, hb);
    tc_w<<<dim3(10, 32), blk, 0, stream>>>(W_down, 576, 2048, Wt_cat);
    tc_w<<<dim3(32, 32), blk, 0, stream>>>(W_q, 2048, 2048, Wt_cat + (size_t)640 * 2048);
    tc_w<<<dim3(48, 8),  blk, 0, stream>>>(W_up, 3072, 512, Wt_up);
    tc_w<<<dim3(32, 32), blk, 0, stream>>>(W_o, 2048, 2048, Wt_o);

    // fused (kv_down | q) = hb @ Wt_cat^T
    gemm_bf16<true><<<dim3(QKD_LD / 128, 32), blk, 0, stream>>>(
        hb, 2048, 2048, Wt_cat, qkd, QKD_LD, QKD_LD);
    // kv = kv_compressed @ W_up  (A = qkd cols 0..511, lda=2688)
    gemm_bf16<true><<<dim3(24, 32), blk, 0, stream>>>(
        qkd, QKD_LD, 512, Wt_up, kvu_b, 3072, 3072);

    transpose_v<<<dim3(S_LEN / 64, 2 * HEADS, BATCH), blk, 0, stream>>>(kvu_b, vTb);

    mla_attn_mfma<<<dim3(S_LEN / 128, HEADS, BATCH), blk, 0, stream>>>(
        qkd, kvu_b, vTb, mask, ctxb);

    gemm_bf16<false><<<dim3(16, 32), blk, 0, stream>>>(
        ctxb, 2048, 2048, Wt_o, out, 2048, 2048);
}